// Round 2
// baseline (688.675 us; speedup 1.0000x reference)
//
#include <hip/hip_runtime.h>
#include <math.h>

#define TT 256
#define FF 64
#define HH 20
#define G4 80   // 4*H
#define EPB 4   // batch elems per block
#define BLK 320 // 4 * 80 threads

__device__ __forceinline__ float sigmoidf_(float z) {
    return 1.0f / (1.0f + __expf(-z));
}

// thread = (elem, j) with j = u*4 + g; weight column col = g*20 + u.
// Gate quad (u fixed, g=0..3) is 4-aligned in lane space -> __shfl_xor combine.
// Weights pinned into VGPRs via empty inline-asm (prevents remat/reload).
__global__ __launch_bounds__(BLK, 3) void lstm2_fused(
    const float* __restrict__ x,
    const float* __restrict__ W1, const float* __restrict__ U1, const float* __restrict__ b1,
    const float* __restrict__ W2, const float* __restrict__ U2, const float* __restrict__ b2,
    const float* __restrict__ Wd, const float* __restrict__ bd,
    float* __restrict__ out)
{
    const int tid  = threadIdx.x;
    const int elem = tid / G4;          // 0..3
    const int j    = tid - elem * G4;   // 0..79
    const int g    = j & 3;             // gate: 0=i 1=f 2=g 3=o
    const int u    = j >> 2;            // hidden unit 0..19
    const int col  = g * HH + u;        // weight column
    const int b0   = blockIdx.x * EPB;

    __shared__ float xs[2][EPB][FF];    // x tile, double buffered
    __shared__ float h1b[2][EPB][24];   // h1 (padded rows)
    __shared__ float h2b[2][EPB][24];

    // ---- load this thread's weight columns into registers ----
    float w1[FF], u1[HH], w2[HH], u2[HH];
#pragma unroll
    for (int f = 0; f < FF; ++f) w1[f] = W1[f * G4 + col];
#pragma unroll
    for (int k = 0; k < HH; ++k) u1[k] = U1[k * G4 + col];
#pragma unroll
    for (int k = 0; k < HH; ++k) w2[k] = W2[k * G4 + col];
#pragma unroll
    for (int k = 0; k < HH; ++k) u2[k] = U2[k * G4 + col];
    const float bias1 = b1[col];
    const float bias2 = b2[col];
    // pin: make values opaque so the compiler must keep them in VGPRs
#pragma unroll
    for (int f = 0; f < FF; ++f) asm volatile("" : "+v"(w1[f]));
#pragma unroll
    for (int k = 0; k < HH; ++k) asm volatile("" : "+v"(u1[k]));
#pragma unroll
    for (int k = 0; k < HH; ++k) asm volatile("" : "+v"(w2[k]));
#pragma unroll
    for (int k = 0; k < HH; ++k) asm volatile("" : "+v"(u2[k]));

    // ---- init LDS ----
    for (int i = tid; i < 2 * EPB * 24; i += BLK) ((float*)h1b)[i] = 0.f;
    for (int i = tid; i < 2 * EPB * 24; i += BLK) ((float*)h2b)[i] = 0.f;
    if (tid < EPB * FF) {
        int e2 = tid >> 6, f2 = tid & 63;
        xs[0][e2][f2] = x[((long)(b0 + e2) * TT + 0) * FF + f2];
    }
    __syncthreads();

    float c1 = 0.f, c2 = 0.f;  // cell state (meaningful in g==0 lanes)

    for (int t = 0; t < TT; ++t) {
        const int cur = t & 1;

        // prefetch next timestep's x into a register
        float xpre = 0.f;
        const int t2 = t + 1;
        if (t2 < TT && tid < EPB * FF) {
            int e2 = tid >> 6, f2 = tid & 63;
            xpre = x[((long)(b0 + e2) * TT + t2) * FF + f2];
        }

        // ---------------- layer 1: z = b1 + x@W1 + h1@U1 (4 indep chains) ----
        float zz0 = 0.f, zz1 = 0.f, zz2 = 0.f, zz3 = 0.f;
        const float4* xv = (const float4*)xs[cur][elem];
#pragma unroll
        for (int q = 0; q < FF / 4; ++q) {
            float4 xx = xv[q];
            zz0 = fmaf(xx.x, w1[4*q+0], zz0);
            zz1 = fmaf(xx.y, w1[4*q+1], zz1);
            zz2 = fmaf(xx.z, w1[4*q+2], zz2);
            zz3 = fmaf(xx.w, w1[4*q+3], zz3);
        }
        const float4* hv = (const float4*)h1b[cur][elem];
#pragma unroll
        for (int q = 0; q < HH / 4; ++q) {
            float4 hh = hv[q];
            zz0 = fmaf(hh.x, u1[4*q+0], zz0);
            zz1 = fmaf(hh.y, u1[4*q+1], zz1);
            zz2 = fmaf(hh.z, u1[4*q+2], zz2);
            zz3 = fmaf(hh.w, u1[4*q+3], zz3);
        }
        float z = bias1 + ((zz0 + zz1) + (zz2 + zz3));

        // own-gate activation, then gather the quad via shuffles
        float a = (g == 2) ? fmaxf(z, 0.f) : sigmoidf_(z);
        float a1 = __shfl_xor(a, 1);
        float a2 = __shfl_xor(a, 2);
        float a3 = __shfl_xor(a, 3);
        // valid in g==0 lanes: i=a, f=a1, g=a2, o=a3
        c1 = a1 * c1 + a * a2;
        float h1n = a3 * fmaxf(c1, 0.f);
        if (g == 0) h1b[cur ^ 1][elem][u] = h1n;
        __syncthreads();   // h1(t) visible; xs[cur]/h1b[cur] reads complete

        // write prefetched x into the other buffer
        if (t2 < TT && tid < EPB * FF) {
            xs[cur ^ 1][tid >> 6][tid & 63] = xpre;
        }

        // ---------------- layer 2: z2 = b2 + h1(t)@W2 + h2@U2 ----------------
        float y0 = 0.f, y1 = 0.f, y2 = 0.f, y3 = 0.f;
        const float4* h1v = (const float4*)h1b[cur ^ 1][elem];  // h1(t)
        const float4* h2v = (const float4*)h2b[cur][elem];      // h2(t-1)
#pragma unroll
        for (int q = 0; q < HH / 4; ++q) {
            float4 ha = h1v[q];
            float4 hb = h2v[q];
            y0 = fmaf(ha.x, w2[4*q+0], y0);
            y1 = fmaf(ha.y, w2[4*q+1], y1);
            y2 = fmaf(ha.z, w2[4*q+2], y2);
            y3 = fmaf(ha.w, w2[4*q+3], y3);
            y0 = fmaf(hb.x, u2[4*q+0], y0);
            y1 = fmaf(hb.y, u2[4*q+1], y1);
            y2 = fmaf(hb.z, u2[4*q+2], y2);
            y3 = fmaf(hb.w, u2[4*q+3], y3);
        }
        float z2v = bias2 + ((y0 + y1) + (y2 + y3));

        float b_ = (g == 2) ? fmaxf(z2v, 0.f) : sigmoidf_(z2v);
        float b1_ = __shfl_xor(b_, 1);
        float b2_ = __shfl_xor(b_, 2);
        float b3_ = __shfl_xor(b_, 3);
        c2 = b1_ * c2 + b_ * b2_;
        float h2n = b3_ * fmaxf(c2, 0.f);
        if (g == 0) h2b[cur ^ 1][elem][u] = h2n;
        __syncthreads();   // h2(t) + xs[cur^1] visible
    }

    // ---------------- dense head: out[b] = h2(T-1) @ Wd + bd ----------------
    // t=255: cur=1, final h2 written to h2b[0]
    if (j == 0) {
        float acc = bd[0];
#pragma unroll
        for (int k = 0; k < HH; ++k) acc += h2b[0][elem][k] * Wd[k];
        out[b0 + elem] = acc;
    }
}

extern "C" void kernel_launch(void* const* d_in, const int* in_sizes, int n_in,
                              void* d_out, int out_size, void* d_ws, size_t ws_size,
                              hipStream_t stream) {
    const float* x  = (const float*)d_in[0];
    const float* W1 = (const float*)d_in[1];
    const float* U1 = (const float*)d_in[2];
    const float* b1 = (const float*)d_in[3];
    const float* W2 = (const float*)d_in[4];
    const float* U2 = (const float*)d_in[5];
    const float* b2 = (const float*)d_in[6];
    const float* Wd = (const float*)d_in[7];
    const float* bd = (const float*)d_in[8];
    float* out = (float*)d_out;
    const int B = in_sizes[0] / (TT * FF);   // 2048
    dim3 grid(B / EPB), block(BLK);
    hipLaunchKernelGGL(lstm2_fused, grid, block, 0, stream,
                       x, W1, U1, b1, W2, U2, b2, Wd, bd, out);
}

// Round 3
// 337.792 us; speedup vs baseline: 2.0388x; 2.0388x over previous
//
#include <hip/hip_runtime.h>
#include <math.h>

#define TT 256
#define FF 64
#define HH 20
#define G4 80   // 4*H
#define EPB 4   // batch elems per block (recurrent kernel)
#define BLK 320
#define TC 64   // t-chunk per proj block

__device__ __forceinline__ float sigmoidf_(float z) {
    return 1.0f / (1.0f + __expf(-z));
}

// ================= K1: xw[t][b][col] = b1[col] + sum_f x[b][t][f]*W1[f][col] =================
// block = (b, t-chunk of 64). x tile + W1 staged in LDS; thread computes a 4t x 4col register tile.
__global__ __launch_bounds__(BLK, 2) void proj_x(
    const float* __restrict__ x, const float* __restrict__ W1,
    const float* __restrict__ b1, float* __restrict__ xw, int B)
{
    __shared__ float xs[TC][FF + 4];   // row stride 68 floats = 272 B (16B-aligned, de-conflicted)
    __shared__ float ws[FF][G4];       // 20 KB
    __shared__ float bs[G4];
    const int tid = threadIdx.x;
    const int b   = blockIdx.x >> 2;
    const int t0  = (blockIdx.x & 3) * TC;

    // stage x tile (contiguous in global), scatter into padded LDS rows
    const float4* xg = (const float4*)(x + ((size_t)b * TT + t0) * FF);
    for (int i = tid; i < TC * FF / 4; i += BLK) {
        int t = i >> 4, q = i & 15;
        *(float4*)&xs[t][q * 4] = xg[i];
    }
    const float4* wg = (const float4*)W1;
    float4* wsv = (float4*)ws;
    for (int i = tid; i < FF * G4 / 4; i += BLK) wsv[i] = wg[i];
    if (tid < G4) bs[tid] = b1[tid];
    __syncthreads();

    const int colq = tid % 20;   // 20 col-quads cover 80 cols
    const int tq   = tid / 20;   // 16 t-quads cover 64 t's
    const int c0   = colq * 4;
    const int tb   = tq * 4;

    const float4 bias4 = *(const float4*)&bs[c0];
    float4 acc[4];
#pragma unroll
    for (int i = 0; i < 4; ++i) acc[i] = bias4;

#pragma unroll 16
    for (int f = 0; f < FF; ++f) {
        float4 wv = *(const float4*)&ws[f][c0];
        float x0 = xs[tb + 0][f], x1 = xs[tb + 1][f];
        float x2 = xs[tb + 2][f], x3 = xs[tb + 3][f];
        acc[0].x = fmaf(x0, wv.x, acc[0].x); acc[0].y = fmaf(x0, wv.y, acc[0].y);
        acc[0].z = fmaf(x0, wv.z, acc[0].z); acc[0].w = fmaf(x0, wv.w, acc[0].w);
        acc[1].x = fmaf(x1, wv.x, acc[1].x); acc[1].y = fmaf(x1, wv.y, acc[1].y);
        acc[1].z = fmaf(x1, wv.z, acc[1].z); acc[1].w = fmaf(x1, wv.w, acc[1].w);
        acc[2].x = fmaf(x2, wv.x, acc[2].x); acc[2].y = fmaf(x2, wv.y, acc[2].y);
        acc[2].z = fmaf(x2, wv.z, acc[2].z); acc[2].w = fmaf(x2, wv.w, acc[2].w);
        acc[3].x = fmaf(x3, wv.x, acc[3].x); acc[3].y = fmaf(x3, wv.y, acc[3].y);
        acc[3].z = fmaf(x3, wv.z, acc[3].z); acc[3].w = fmaf(x3, wv.w, acc[3].w);
    }
#pragma unroll
    for (int i = 0; i < 4; ++i) {
        *(float4*)&xw[((size_t)(t0 + tb + i) * B + b) * G4 + c0] = acc[i];
    }
}

// ================= K2: recurrence. thread = (elem, col); only U1/W2/U2 in regs =================
__global__ __launch_bounds__(BLK, 3) void lstm2_rec(
    const float* __restrict__ xw,
    const float* __restrict__ U1,
    const float* __restrict__ W2, const float* __restrict__ U2, const float* __restrict__ b2,
    const float* __restrict__ Wd, const float* __restrict__ bd,
    float* __restrict__ out, int B)
{
    const int tid  = threadIdx.x;
    const int elem = tid / G4;          // 0..3
    const int j    = tid - elem * G4;   // 0..79
    const int g    = j & 3;             // gate: 0=i 1=f 2=c 3=o
    const int u    = j >> 2;            // unit 0..19
    const int col  = g * HH + u;
    const int b0   = blockIdx.x * EPB;

    __shared__ float h1b[2][EPB][24];
    __shared__ float h2b[2][EPB][24];

    float u1r[HH], w2r[HH], u2r[HH];
#pragma unroll
    for (int k = 0; k < HH; ++k) u1r[k] = U1[k * G4 + col];
#pragma unroll
    for (int k = 0; k < HH; ++k) w2r[k] = W2[k * G4 + col];
#pragma unroll
    for (int k = 0; k < HH; ++k) u2r[k] = U2[k * G4 + col];
    const float bias2 = b2[col];

    for (int i = tid; i < 2 * EPB * 24; i += BLK) ((float*)h1b)[i] = 0.f;
    for (int i = tid; i < 2 * EPB * 24; i += BLK) ((float*)h2b)[i] = 0.f;
    __syncthreads();

    const float* xwp = xw + (size_t)(b0 + elem) * G4 + col;
    const size_t tstride = (size_t)B * G4;
    float xwc = xwp[0];                 // xw at t=0
    float c1 = 0.f, c2 = 0.f;

    for (int t = 0; t < TT; ++t) {
        const int cur = t & 1;

        // prefetch next step's xw (one coalesced load per wave)
        float xwn = 0.f;
        if (t + 1 < TT) xwn = xwp[(size_t)(t + 1) * tstride];

        // -------- layer 1: z = xw + h1(t-1) @ U1 --------
        float zz0 = 0.f, zz1 = 0.f, zz2 = 0.f, zz3 = 0.f;
        const float4* hv = (const float4*)h1b[cur][elem];
#pragma unroll
        for (int q = 0; q < HH / 4; ++q) {
            float4 hh = hv[q];
            zz0 = fmaf(hh.x, u1r[4*q+0], zz0);
            zz1 = fmaf(hh.y, u1r[4*q+1], zz1);
            zz2 = fmaf(hh.z, u1r[4*q+2], zz2);
            zz3 = fmaf(hh.w, u1r[4*q+3], zz3);
        }
        float z = xwc + ((zz0 + zz1) + (zz2 + zz3));

        float a = (g == 2) ? fmaxf(z, 0.f) : sigmoidf_(z);
        float a1 = __shfl_xor(a, 1);
        float a2 = __shfl_xor(a, 2);
        float a3 = __shfl_xor(a, 3);
        // valid in g==0 lanes: i=a, f=a1, c=a2, o=a3
        c1 = a1 * c1 + a * a2;
        float h1n = a3 * fmaxf(c1, 0.f);
        if (g == 0) h1b[cur ^ 1][elem][u] = h1n;
        __syncthreads();

        // -------- layer 2: z2 = b2 + h1(t) @ W2 + h2(t-1) @ U2 --------
        float y0 = 0.f, y1 = 0.f, y2 = 0.f, y3 = 0.f;
        const float4* h1v = (const float4*)h1b[cur ^ 1][elem];
        const float4* h2v = (const float4*)h2b[cur][elem];
#pragma unroll
        for (int q = 0; q < HH / 4; ++q) {
            float4 ha = h1v[q];
            float4 hb = h2v[q];
            y0 = fmaf(ha.x, w2r[4*q+0], y0);
            y1 = fmaf(ha.y, w2r[4*q+1], y1);
            y2 = fmaf(ha.z, w2r[4*q+2], y2);
            y3 = fmaf(ha.w, w2r[4*q+3], y3);
            y0 = fmaf(hb.x, u2r[4*q+0], y0);
            y1 = fmaf(hb.y, u2r[4*q+1], y1);
            y2 = fmaf(hb.z, u2r[4*q+2], y2);
            y3 = fmaf(hb.w, u2r[4*q+3], y3);
        }
        float z2v = bias2 + ((y0 + y1) + (y2 + y3));

        float bgt = (g == 2) ? fmaxf(z2v, 0.f) : sigmoidf_(z2v);
        float b1_ = __shfl_xor(bgt, 1);
        float b2_ = __shfl_xor(bgt, 2);
        float b3_ = __shfl_xor(bgt, 3);
        c2 = b1_ * c2 + bgt * b2_;
        float h2n = b3_ * fmaxf(c2, 0.f);
        if (g == 0) h2b[cur ^ 1][elem][u] = h2n;
        __syncthreads();

        xwc = xwn;
    }

    // dense head: final h2 is in h2b[0] (t=255 writes cur^1 = 0)
    if (j == 0) {
        float acc = bd[0];
#pragma unroll
        for (int k = 0; k < HH; ++k) acc += h2b[0][elem][k] * Wd[k];
        out[b0 + elem] = acc;
    }
}

// ================= Fallback (ws too small): fused kernel, weights unpinned =================
__global__ __launch_bounds__(BLK, 2) void lstm2_fused_fb(
    const float* __restrict__ x,
    const float* __restrict__ W1, const float* __restrict__ U1, const float* __restrict__ b1,
    const float* __restrict__ W2, const float* __restrict__ U2, const float* __restrict__ b2,
    const float* __restrict__ Wd, const float* __restrict__ bd,
    float* __restrict__ out)
{
    const int tid  = threadIdx.x;
    const int elem = tid / G4;
    const int j    = tid - elem * G4;
    const int g    = j & 3;
    const int u    = j >> 2;
    const int col  = g * HH + u;
    const int b0   = blockIdx.x * EPB;

    __shared__ float xs[2][EPB][FF];
    __shared__ float h1b[2][EPB][24];
    __shared__ float h2b[2][EPB][24];

    float w1[FF], u1[HH], w2[HH], u2[HH];
#pragma unroll
    for (int f = 0; f < FF; ++f) w1[f] = W1[f * G4 + col];
#pragma unroll
    for (int k = 0; k < HH; ++k) u1[k] = U1[k * G4 + col];
#pragma unroll
    for (int k = 0; k < HH; ++k) w2[k] = W2[k * G4 + col];
#pragma unroll
    for (int k = 0; k < HH; ++k) u2[k] = U2[k * G4 + col];
    const float bias1 = b1[col];
    const float bias2 = b2[col];

    for (int i = tid; i < 2 * EPB * 24; i += BLK) ((float*)h1b)[i] = 0.f;
    for (int i = tid; i < 2 * EPB * 24; i += BLK) ((float*)h2b)[i] = 0.f;
    if (tid < EPB * FF) {
        int e2 = tid >> 6, f2 = tid & 63;
        xs[0][e2][f2] = x[((long)(b0 + e2) * TT + 0) * FF + f2];
    }
    __syncthreads();

    float c1 = 0.f, c2 = 0.f;
    for (int t = 0; t < TT; ++t) {
        const int cur = t & 1;
        float xpre = 0.f;
        if (t + 1 < TT && tid < EPB * FF) {
            int e2 = tid >> 6, f2 = tid & 63;
            xpre = x[((long)(b0 + e2) * TT + (t + 1)) * FF + f2];
        }
        float zz0 = 0.f, zz1 = 0.f, zz2 = 0.f, zz3 = 0.f;
        const float4* xv = (const float4*)xs[cur][elem];
#pragma unroll
        for (int q = 0; q < FF / 4; ++q) {
            float4 xx = xv[q];
            zz0 = fmaf(xx.x, w1[4*q+0], zz0);
            zz1 = fmaf(xx.y, w1[4*q+1], zz1);
            zz2 = fmaf(xx.z, w1[4*q+2], zz2);
            zz3 = fmaf(xx.w, w1[4*q+3], zz3);
        }
        const float4* hv = (const float4*)h1b[cur][elem];
#pragma unroll
        for (int q = 0; q < HH / 4; ++q) {
            float4 hh = hv[q];
            zz0 = fmaf(hh.x, u1[4*q+0], zz0);
            zz1 = fmaf(hh.y, u1[4*q+1], zz1);
            zz2 = fmaf(hh.z, u1[4*q+2], zz2);
            zz3 = fmaf(hh.w, u1[4*q+3], zz3);
        }
        float z = bias1 + ((zz0 + zz1) + (zz2 + zz3));
        float a = (g == 2) ? fmaxf(z, 0.f) : sigmoidf_(z);
        float a1 = __shfl_xor(a, 1), a2 = __shfl_xor(a, 2), a3 = __shfl_xor(a, 3);
        c1 = a1 * c1 + a * a2;
        float h1n = a3 * fmaxf(c1, 0.f);
        if (g == 0) h1b[cur ^ 1][elem][u] = h1n;
        __syncthreads();
        if (t + 1 < TT && tid < EPB * FF) xs[cur ^ 1][tid >> 6][tid & 63] = xpre;

        float y0 = 0.f, y1 = 0.f, y2 = 0.f, y3 = 0.f;
        const float4* h1v = (const float4*)h1b[cur ^ 1][elem];
        const float4* h2v = (const float4*)h2b[cur][elem];
#pragma unroll
        for (int q = 0; q < HH / 4; ++q) {
            float4 ha = h1v[q];
            float4 hb = h2v[q];
            y0 = fmaf(ha.x, w2[4*q+0], y0);
            y1 = fmaf(ha.y, w2[4*q+1], y1);
            y2 = fmaf(ha.z, w2[4*q+2], y2);
            y3 = fmaf(ha.w, w2[4*q+3], y3);
            y0 = fmaf(hb.x, u2[4*q+0], y0);
            y1 = fmaf(hb.y, u2[4*q+1], y1);
            y2 = fmaf(hb.z, u2[4*q+2], y2);
            y3 = fmaf(hb.w, u2[4*q+3], y3);
        }
        float z2v = bias2 + ((y0 + y1) + (y2 + y3));
        float bgt = (g == 2) ? fmaxf(z2v, 0.f) : sigmoidf_(z2v);
        float b1_ = __shfl_xor(bgt, 1), b2_ = __shfl_xor(bgt, 2), b3_ = __shfl_xor(bgt, 3);
        c2 = b1_ * c2 + bgt * b2_;
        float h2n = b3_ * fmaxf(c2, 0.f);
        if (g == 0) h2b[cur ^ 1][elem][u] = h2n;
        __syncthreads();
    }
    if (j == 0) {
        float acc = bd[0];
#pragma unroll
        for (int k = 0; k < HH; ++k) acc += h2b[0][elem][k] * Wd[k];
        out[b0 + elem] = acc;
    }
}

extern "C" void kernel_launch(void* const* d_in, const int* in_sizes, int n_in,
                              void* d_out, int out_size, void* d_ws, size_t ws_size,
                              hipStream_t stream) {
    const float* x  = (const float*)d_in[0];
    const float* W1 = (const float*)d_in[1];
    const float* U1 = (const float*)d_in[2];
    const float* b1 = (const float*)d_in[3];
    const float* W2 = (const float*)d_in[4];
    const float* U2 = (const float*)d_in[5];
    const float* b2 = (const float*)d_in[6];
    const float* Wd = (const float*)d_in[7];
    const float* bd = (const float*)d_in[8];
    float* out = (float*)d_out;
    const int B = in_sizes[0] / (TT * FF);   // 2048

    const size_t need = (size_t)B * TT * G4 * sizeof(float);  // 167.8 MB
    if (ws_size >= need) {
        float* xw = (float*)d_ws;
        hipLaunchKernelGGL(proj_x, dim3(B * (TT / TC)), dim3(BLK), 0, stream,
                           x, W1, b1, xw, B);
        hipLaunchKernelGGL(lstm2_rec, dim3(B / EPB), dim3(BLK), 0, stream,
                           xw, U1, W2, U2, b2, Wd, bd, out, B);
    } else {
        hipLaunchKernelGGL(lstm2_fused_fb, dim3(B / EPB), dim3(BLK), 0, stream,
                           x, W1, U1, b1, W2, U2, b2, Wd, bd, out);
    }
}

// Round 4
// 333.232 us; speedup vs baseline: 2.0667x; 1.0137x over previous
//
#include <hip/hip_runtime.h>
#include <math.h>

#define TT 256
#define FF 64
#define HH 20
#define G4 80   // 4*H
#define EPB 4   // batch elems per block (recurrent kernel)
#define BLK 320
#define TC 64   // t-chunk per proj block

__device__ __forceinline__ float sigmoidf_(float z) {
    return 1.0f / (1.0f + __expf(-z));
}

// ================= K1: xw[t][b][col] = b1[col] + sum_f x[b][t][f]*W1[f][col] =================
__global__ __launch_bounds__(BLK, 2) void proj_x(
    const float* __restrict__ x, const float* __restrict__ W1,
    const float* __restrict__ b1, float* __restrict__ xw, int B)
{
    __shared__ float xs[TC][FF + 4];   // padded rows (de-conflicted)
    __shared__ float ws[FF][G4];       // 20 KB
    __shared__ float bs[G4];
    const int tid = threadIdx.x;
    const int b   = blockIdx.x >> 2;
    const int t0  = (blockIdx.x & 3) * TC;

    const float4* xg = (const float4*)(x + ((size_t)b * TT + t0) * FF);
    for (int i = tid; i < TC * FF / 4; i += BLK) {
        int t = i >> 4, q = i & 15;
        *(float4*)&xs[t][q * 4] = xg[i];
    }
    const float4* wg = (const float4*)W1;
    float4* wsv = (float4*)ws;
    for (int i = tid; i < FF * G4 / 4; i += BLK) wsv[i] = wg[i];
    if (tid < G4) bs[tid] = b1[tid];
    __syncthreads();

    const int colq = tid % 20;
    const int tq   = tid / 20;
    const int c0   = colq * 4;
    const int tb   = tq * 4;

    const float4 bias4 = *(const float4*)&bs[c0];
    float4 acc[4];
#pragma unroll
    for (int i = 0; i < 4; ++i) acc[i] = bias4;

#pragma unroll 16
    for (int f = 0; f < FF; ++f) {
        float4 wv = *(const float4*)&ws[f][c0];
        float x0 = xs[tb + 0][f], x1 = xs[tb + 1][f];
        float x2 = xs[tb + 2][f], x3 = xs[tb + 3][f];
        acc[0].x = fmaf(x0, wv.x, acc[0].x); acc[0].y = fmaf(x0, wv.y, acc[0].y);
        acc[0].z = fmaf(x0, wv.z, acc[0].z); acc[0].w = fmaf(x0, wv.w, acc[0].w);
        acc[1].x = fmaf(x1, wv.x, acc[1].x); acc[1].y = fmaf(x1, wv.y, acc[1].y);
        acc[1].z = fmaf(x1, wv.z, acc[1].z); acc[1].w = fmaf(x1, wv.w, acc[1].w);
        acc[2].x = fmaf(x2, wv.x, acc[2].x); acc[2].y = fmaf(x2, wv.y, acc[2].y);
        acc[2].z = fmaf(x2, wv.z, acc[2].z); acc[2].w = fmaf(x2, wv.w, acc[2].w);
        acc[3].x = fmaf(x3, wv.x, acc[3].x); acc[3].y = fmaf(x3, wv.y, acc[3].y);
        acc[3].z = fmaf(x3, wv.z, acc[3].z); acc[3].w = fmaf(x3, wv.w, acc[3].w);
    }
#pragma unroll
    for (int i = 0; i < 4; ++i) {
        *(float4*)&xw[((size_t)(t0 + tb + i) * B + b) * G4 + c0] = acc[i];
    }
}

// ================= K2: recurrence. thread = (elem, col); U1/W2/U2 pinned in VGPRs =================
// 60 weights + ~40 working regs ≈ 100 VGPR < 256 cap (launch_bounds min-waves=2).
// Occupancy is grid-limited (512 blocks = 2/CU) so the relaxed cap costs nothing.
__global__ __launch_bounds__(BLK, 2) void lstm2_rec(
    const float* __restrict__ xw,
    const float* __restrict__ U1,
    const float* __restrict__ W2, const float* __restrict__ U2, const float* __restrict__ b2,
    const float* __restrict__ Wd, const float* __restrict__ bd,
    float* __restrict__ out, int B)
{
    const int tid  = threadIdx.x;
    const int elem = tid / G4;          // 0..3
    const int j    = tid - elem * G4;   // 0..79
    const int g    = j & 3;             // gate: 0=i 1=f 2=c 3=o
    const int u    = j >> 2;            // unit 0..19
    const int col  = g * HH + u;
    const int b0   = blockIdx.x * EPB;

    __shared__ float h1b[2][EPB][24];
    __shared__ float h2b[2][EPB][24];

    float u1r[HH], w2r[HH], u2r[HH];
#pragma unroll
    for (int k = 0; k < HH; ++k) u1r[k] = U1[k * G4 + col];
#pragma unroll
    for (int k = 0; k < HH; ++k) w2r[k] = W2[k * G4 + col];
#pragma unroll
    for (int k = 0; k < HH; ++k) u2r[k] = U2[k * G4 + col];
    const float bias2 = b2[col];
    // pin: force true VGPR residency (fits this time: ~100 < 256 cap)
#pragma unroll
    for (int k = 0; k < HH; ++k) asm volatile("" : "+v"(u1r[k]));
#pragma unroll
    for (int k = 0; k < HH; ++k) asm volatile("" : "+v"(w2r[k]));
#pragma unroll
    for (int k = 0; k < HH; ++k) asm volatile("" : "+v"(u2r[k]));

    for (int i = tid; i < 2 * EPB * 24; i += BLK) ((float*)h1b)[i] = 0.f;
    for (int i = tid; i < 2 * EPB * 24; i += BLK) ((float*)h2b)[i] = 0.f;
    __syncthreads();

    const float* xwp = xw + (size_t)(b0 + elem) * G4 + col;
    const size_t tstride = (size_t)B * G4;
    float xwc = xwp[0];                 // xw at t=0
    float c1 = 0.f, c2 = 0.f;

    for (int t = 0; t < TT; ++t) {
        const int cur = t & 1;

        // prefetch next step's xw (coalesced; hides under the step's compute)
        float xwn = 0.f;
        if (t + 1 < TT) xwn = xwp[(size_t)(t + 1) * tstride];

        // -------- layer 1: z = xw + h1(t-1) @ U1 --------
        float zz0 = 0.f, zz1 = 0.f, zz2 = 0.f, zz3 = 0.f;
        const float4* hv = (const float4*)h1b[cur][elem];
#pragma unroll
        for (int q = 0; q < HH / 4; ++q) {
            float4 hh = hv[q];
            zz0 = fmaf(hh.x, u1r[4*q+0], zz0);
            zz1 = fmaf(hh.y, u1r[4*q+1], zz1);
            zz2 = fmaf(hh.z, u1r[4*q+2], zz2);
            zz3 = fmaf(hh.w, u1r[4*q+3], zz3);
        }
        float z = xwc + ((zz0 + zz1) + (zz2 + zz3));

        float a = (g == 2) ? fmaxf(z, 0.f) : sigmoidf_(z);
        float a1 = __shfl_xor(a, 1);
        float a2 = __shfl_xor(a, 2);
        float a3 = __shfl_xor(a, 3);
        // valid in g==0 lanes: i=a, f=a1, c=a2, o=a3
        c1 = a1 * c1 + a * a2;
        float h1n = a3 * fmaxf(c1, 0.f);
        if (g == 0) h1b[cur ^ 1][elem][u] = h1n;
        __syncthreads();

        // -------- layer 2: z2 = b2 + h1(t) @ W2 + h2(t-1) @ U2 --------
        float y0 = 0.f, y1 = 0.f, y2 = 0.f, y3 = 0.f;
        const float4* h1v = (const float4*)h1b[cur ^ 1][elem];
        const float4* h2v = (const float4*)h2b[cur][elem];
#pragma unroll
        for (int q = 0; q < HH / 4; ++q) {
            float4 ha = h1v[q];
            float4 hb = h2v[q];
            y0 = fmaf(ha.x, w2r[4*q+0], y0);
            y1 = fmaf(ha.y, w2r[4*q+1], y1);
            y2 = fmaf(ha.z, w2r[4*q+2], y2);
            y3 = fmaf(ha.w, w2r[4*q+3], y3);
            y0 = fmaf(hb.x, u2r[4*q+0], y0);
            y1 = fmaf(hb.y, u2r[4*q+1], y1);
            y2 = fmaf(hb.z, u2r[4*q+2], y2);
            y3 = fmaf(hb.w, u2r[4*q+3], y3);
        }
        float z2v = bias2 + ((y0 + y1) + (y2 + y3));

        float bgt = (g == 2) ? fmaxf(z2v, 0.f) : sigmoidf_(z2v);
        float b1_ = __shfl_xor(bgt, 1);
        float b2_ = __shfl_xor(bgt, 2);
        float b3_ = __shfl_xor(bgt, 3);
        c2 = b1_ * c2 + bgt * b2_;
        float h2n = b3_ * fmaxf(c2, 0.f);
        if (g == 0) h2b[cur ^ 1][elem][u] = h2n;
        __syncthreads();

        xwc = xwn;
    }

    // dense head: final h2 is in h2b[0] (t=255 writes cur^1 = 0)
    if (j == 0) {
        float acc = bd[0];
#pragma unroll
        for (int k = 0; k < HH; ++k) acc += h2b[0][elem][k] * Wd[k];
        out[b0 + elem] = acc;
    }
}

// ================= Fallback (ws too small): fused kernel =================
__global__ __launch_bounds__(BLK, 2) void lstm2_fused_fb(
    const float* __restrict__ x,
    const float* __restrict__ W1, const float* __restrict__ U1, const float* __restrict__ b1,
    const float* __restrict__ W2, const float* __restrict__ U2, const float* __restrict__ b2,
    const float* __restrict__ Wd, const float* __restrict__ bd,
    float* __restrict__ out)
{
    const int tid  = threadIdx.x;
    const int elem = tid / G4;
    const int j    = tid - elem * G4;
    const int g    = j & 3;
    const int u    = j >> 2;
    const int col  = g * HH + u;
    const int b0   = blockIdx.x * EPB;

    __shared__ float xs[2][EPB][FF];
    __shared__ float h1b[2][EPB][24];
    __shared__ float h2b[2][EPB][24];

    float w1[FF], u1[HH], w2[HH], u2[HH];
#pragma unroll
    for (int f = 0; f < FF; ++f) w1[f] = W1[f * G4 + col];
#pragma unroll
    for (int k = 0; k < HH; ++k) u1[k] = U1[k * G4 + col];
#pragma unroll
    for (int k = 0; k < HH; ++k) w2[k] = W2[k * G4 + col];
#pragma unroll
    for (int k = 0; k < HH; ++k) u2[k] = U2[k * G4 + col];
    const float bias1 = b1[col];
    const float bias2 = b2[col];

    for (int i = tid; i < 2 * EPB * 24; i += BLK) ((float*)h1b)[i] = 0.f;
    for (int i = tid; i < 2 * EPB * 24; i += BLK) ((float*)h2b)[i] = 0.f;
    if (tid < EPB * FF) {
        int e2 = tid >> 6, f2 = tid & 63;
        xs[0][e2][f2] = x[((long)(b0 + e2) * TT + 0) * FF + f2];
    }
    __syncthreads();

    float c1 = 0.f, c2 = 0.f;
    for (int t = 0; t < TT; ++t) {
        const int cur = t & 1;
        float xpre = 0.f;
        if (t + 1 < TT && tid < EPB * FF) {
            int e2 = tid >> 6, f2 = tid & 63;
            xpre = x[((long)(b0 + e2) * TT + (t + 1)) * FF + f2];
        }
        float zz0 = 0.f, zz1 = 0.f, zz2 = 0.f, zz3 = 0.f;
        const float4* xv = (const float4*)xs[cur][elem];
#pragma unroll
        for (int q = 0; q < FF / 4; ++q) {
            float4 xx = xv[q];
            zz0 = fmaf(xx.x, w1[4*q+0], zz0);
            zz1 = fmaf(xx.y, w1[4*q+1], zz1);
            zz2 = fmaf(xx.z, w1[4*q+2], zz2);
            zz3 = fmaf(xx.w, w1[4*q+3], zz3);
        }
        const float4* hv = (const float4*)h1b[cur][elem];
#pragma unroll
        for (int q = 0; q < HH / 4; ++q) {
            float4 hh = hv[q];
            zz0 = fmaf(hh.x, u1[4*q+0], zz0);
            zz1 = fmaf(hh.y, u1[4*q+1], zz1);
            zz2 = fmaf(hh.z, u1[4*q+2], zz2);
            zz3 = fmaf(hh.w, u1[4*q+3], zz3);
        }
        float z = bias1 + ((zz0 + zz1) + (zz2 + zz3));
        float a = (g == 2) ? fmaxf(z, 0.f) : sigmoidf_(z);
        float a1 = __shfl_xor(a, 1), a2 = __shfl_xor(a, 2), a3 = __shfl_xor(a, 3);
        c1 = a1 * c1 + a * a2;
        float h1n = a3 * fmaxf(c1, 0.f);
        if (g == 0) h1b[cur ^ 1][elem][u] = h1n;
        __syncthreads();
        if (t + 1 < TT && tid < EPB * FF) xs[cur ^ 1][tid >> 6][tid & 63] = xpre;

        float y0 = 0.f, y1 = 0.f, y2 = 0.f, y3 = 0.f;
        const float4* h1v = (const float4*)h1b[cur ^ 1][elem];
        const float4* h2v = (const float4*)h2b[cur][elem];
#pragma unroll
        for (int q = 0; q < HH / 4; ++q) {
            float4 ha = h1v[q];
            float4 hb = h2v[q];
            y0 = fmaf(ha.x, w2[4*q+0], y0);
            y1 = fmaf(ha.y, w2[4*q+1], y1);
            y2 = fmaf(ha.z, w2[4*q+2], y2);
            y3 = fmaf(ha.w, w2[4*q+3], y3);
            y0 = fmaf(hb.x, u2[4*q+0], y0);
            y1 = fmaf(hb.y, u2[4*q+1], y1);
            y2 = fmaf(hb.z, u2[4*q+2], y2);
            y3 = fmaf(hb.w, u2[4*q+3], y3);
        }
        float z2v = bias2 + ((y0 + y1) + (y2 + y3));
        float bgt = (g == 2) ? fmaxf(z2v, 0.f) : sigmoidf_(z2v);
        float b1_ = __shfl_xor(bgt, 1), b2_ = __shfl_xor(bgt, 2), b3_ = __shfl_xor(bgt, 3);
        c2 = b1_ * c2 + bgt * b2_;
        float h2n = b3_ * fmaxf(c2, 0.f);
        if (g == 0) h2b[cur ^ 1][elem][u] = h2n;
        __syncthreads();
    }
    if (j == 0) {
        float acc = bd[0];
#pragma unroll
        for (int k = 0; k < HH; ++k) acc += h2b[0][elem][k] * Wd[k];
        out[b0 + elem] = acc;
    }
}

extern "C" void kernel_launch(void* const* d_in, const int* in_sizes, int n_in,
                              void* d_out, int out_size, void* d_ws, size_t ws_size,
                              hipStream_t stream) {
    const float* x  = (const float*)d_in[0];
    const float* W1 = (const float*)d_in[1];
    const float* U1 = (const float*)d_in[2];
    const float* b1 = (const float*)d_in[3];
    const float* W2 = (const float*)d_in[4];
    const float* U2 = (const float*)d_in[5];
    const float* b2 = (const float*)d_in[6];
    const float* Wd = (const float*)d_in[7];
    const float* bd = (const float*)d_in[8];
    float* out = (float*)d_out;
    const int B = in_sizes[0] / (TT * FF);   // 2048

    const size_t need = (size_t)B * TT * G4 * sizeof(float);  // 167.8 MB
    if (ws_size >= need) {
        float* xw = (float*)d_ws;
        hipLaunchKernelGGL(proj_x, dim3(B * (TT / TC)), dim3(BLK), 0, stream,
                           x, W1, b1, xw, B);
        hipLaunchKernelGGL(lstm2_rec, dim3(B / EPB), dim3(BLK), 0, stream,
                           xw, U1, W2, U2, b2, Wd, bd, out, B);
    } else {
        hipLaunchKernelGGL(lstm2_fused_fb, dim3(B / EPB), dim3(BLK), 0, stream,
                           x, W1, U1, b1, W2, U2, b2, Wd, bd, out);
    }
}

// Round 5
// 293.279 us; speedup vs baseline: 2.3482x; 1.1362x over previous
//
#include <hip/hip_runtime.h>
#include <math.h>

#define TT 256
#define FF 64
#define HH 20
#define G4 80   // 4*H
#define EPB 4   // batch elems per block
#define PBLK 320
#define RBLK 640  // 5 waves L1 + 5 waves L2
#define TC 64

__device__ __forceinline__ float sigmoidf_(float z) {
    return 1.0f / (1.0f + __expf(-z));
}

// quad_perm DPP: value from lane (lane ^ m) within each aligned quad (VALU, no DS)
__device__ __forceinline__ float qpx1(float v) {
    return __int_as_float(__builtin_amdgcn_mov_dpp(__float_as_int(v), 0xB1, 0xF, 0xF, true));
}
__device__ __forceinline__ float qpx2(float v) {
    return __int_as_float(__builtin_amdgcn_mov_dpp(__float_as_int(v), 0x4E, 0xF, 0xF, true));
}
__device__ __forceinline__ float qpx3(float v) {
    return __int_as_float(__builtin_amdgcn_mov_dpp(__float_as_int(v), 0x1B, 0xF, 0xF, true));
}

// ================= K1: xw[t][b][col] = b1[col] + sum_f x[b][t][f]*W1[f][col] =================
__global__ __launch_bounds__(PBLK, 2) void proj_x(
    const float* __restrict__ x, const float* __restrict__ W1,
    const float* __restrict__ b1, float* __restrict__ xw, int B)
{
    __shared__ float xs[TC][FF + 4];
    __shared__ float ws[FF][G4];
    __shared__ float bs[G4];
    const int tid = threadIdx.x;
    const int b   = blockIdx.x >> 2;
    const int t0  = (blockIdx.x & 3) * TC;

    const float4* xg = (const float4*)(x + ((size_t)b * TT + t0) * FF);
    for (int i = tid; i < TC * FF / 4; i += PBLK) {
        int t = i >> 4, q = i & 15;
        *(float4*)&xs[t][q * 4] = xg[i];
    }
    const float4* wg = (const float4*)W1;
    float4* wsv = (float4*)ws;
    for (int i = tid; i < FF * G4 / 4; i += PBLK) wsv[i] = wg[i];
    if (tid < G4) bs[tid] = b1[tid];
    __syncthreads();

    const int colq = tid % 20;
    const int tq   = tid / 20;
    const int c0   = colq * 4;
    const int tb   = tq * 4;

    const float4 bias4 = *(const float4*)&bs[c0];
    float4 acc[4];
#pragma unroll
    for (int i = 0; i < 4; ++i) acc[i] = bias4;

#pragma unroll 16
    for (int f = 0; f < FF; ++f) {
        float4 wv = *(const float4*)&ws[f][c0];
        float x0 = xs[tb + 0][f], x1 = xs[tb + 1][f];
        float x2 = xs[tb + 2][f], x3 = xs[tb + 3][f];
        acc[0].x = fmaf(x0, wv.x, acc[0].x); acc[0].y = fmaf(x0, wv.y, acc[0].y);
        acc[0].z = fmaf(x0, wv.z, acc[0].z); acc[0].w = fmaf(x0, wv.w, acc[0].w);
        acc[1].x = fmaf(x1, wv.x, acc[1].x); acc[1].y = fmaf(x1, wv.y, acc[1].y);
        acc[1].z = fmaf(x1, wv.z, acc[1].z); acc[1].w = fmaf(x1, wv.w, acc[1].w);
        acc[2].x = fmaf(x2, wv.x, acc[2].x); acc[2].y = fmaf(x2, wv.y, acc[2].y);
        acc[2].z = fmaf(x2, wv.z, acc[2].z); acc[2].w = fmaf(x2, wv.w, acc[2].w);
        acc[3].x = fmaf(x3, wv.x, acc[3].x); acc[3].y = fmaf(x3, wv.y, acc[3].y);
        acc[3].z = fmaf(x3, wv.z, acc[3].z); acc[3].w = fmaf(x3, wv.w, acc[3].w);
    }
#pragma unroll
    for (int i = 0; i < 4; ++i) {
        *(float4*)&xw[((size_t)(t0 + tb + i) * B + b) * G4 + c0] = acc[i];
    }
}

// ============ K2: producer-consumer recurrence, 1 barrier/step ============
// Waves 0-4 (tid<320): layer1. Waves 5-9: layer2, one step behind.
// At iter i: L1 computes h1(i) from h1buf[rb]; L2 computes h2(i-1) from h1buf[rb], h2buf[rb].
// rb = (i+1)&1 read buffers, wb = i&1 write buffers; single barrier separates iters.
__global__ __launch_bounds__(RBLK, 2) void lstm2_pc(
    const float* __restrict__ xw,
    const float* __restrict__ U1,
    const float* __restrict__ W2, const float* __restrict__ U2, const float* __restrict__ b2,
    const float* __restrict__ Wd, const float* __restrict__ bd,
    float* __restrict__ out, int B)
{
    const int tid  = threadIdx.x;
    const bool isL1 = tid < 320;
    const int rt   = isL1 ? tid : tid - 320;
    const int elem = rt / G4;          // 0..3
    const int j    = rt - elem * G4;   // 0..79
    const int g    = j & 3;            // gate: 0=i 1=f 2=c 3=o
    const int u    = j >> 2;           // unit 0..19
    const int col  = g * HH + u;
    const int b0   = blockIdx.x * EPB;

    __shared__ float h1b[2][EPB][24];
    __shared__ float h2b[2][EPB][24];

    // role weights: L1 -> wA = U1 col; L2 -> wA = W2 col, wB = U2 col
    float wA[HH], wB[HH];
    float bias = 0.f;
    if (isL1) {
#pragma unroll
        for (int k = 0; k < HH; ++k) wA[k] = U1[k * G4 + col];
#pragma unroll
        for (int k = 0; k < HH; ++k) wB[k] = 0.f;
    } else {
#pragma unroll
        for (int k = 0; k < HH; ++k) wA[k] = W2[k * G4 + col];
#pragma unroll
        for (int k = 0; k < HH; ++k) wB[k] = U2[k * G4 + col];
        bias = b2[col];
    }

    for (int i = tid; i < 2 * EPB * 24; i += RBLK) ((float*)h1b)[i] = 0.f;
    for (int i = tid; i < 2 * EPB * 24; i += RBLK) ((float*)h2b)[i] = 0.f;

    const float* xwp = xw + (size_t)(b0 + elem) * G4 + col;
    const size_t tstride = (size_t)B * G4;
    float xwc = isL1 ? xwp[0] : 0.f;   // xw at t=0 (L1 only; wave-uniform branch)
    float c1 = 0.f, c2 = 0.f;
    __syncthreads();

    for (int i = 0; i <= TT; ++i) {
        const int rb = (i + 1) & 1;    // read buffers (prev iter's writes / zeros)
        const int wb = i & 1;          // write buffers

        if (isL1 && i < TT) {
            // prefetch xw(i+1)
            float xwn = 0.f;
            if (i + 1 < TT) xwn = xwp[(size_t)(i + 1) * tstride];

            // z = xw(i) + h1(i-1) @ U1
            float zz0 = 0.f, zz1 = 0.f, zz2 = 0.f, zz3 = 0.f;
            const float4* hv = (const float4*)h1b[rb][elem];
#pragma unroll
            for (int q = 0; q < HH / 4; ++q) {
                float4 hh = hv[q];
                zz0 = fmaf(hh.x, wA[4*q+0], zz0);
                zz1 = fmaf(hh.y, wA[4*q+1], zz1);
                zz2 = fmaf(hh.z, wA[4*q+2], zz2);
                zz3 = fmaf(hh.w, wA[4*q+3], zz3);
            }
            float z = xwc + ((zz0 + zz1) + (zz2 + zz3));

            float a = (g == 2) ? fmaxf(z, 0.f) : sigmoidf_(z);
            float a1 = qpx1(a), a2 = qpx2(a), a3 = qpx3(a);
            // valid in g==0 lanes: i=a, f=a1, c=a2, o=a3
            c1 = a1 * c1 + a * a2;
            float h1n = a3 * fmaxf(c1, 0.f);
            if (g == 0) h1b[wb][elem][u] = h1n;
            xwc = xwn;
        }
        if (!isL1 && i >= 1) {
            // z2 = b2 + h1(i-1) @ W2 + h2(i-2) @ U2
            float y0 = 0.f, y1 = 0.f, y2 = 0.f, y3 = 0.f;
            const float4* h1v = (const float4*)h1b[rb][elem];
            const float4* h2v = (const float4*)h2b[rb][elem];
#pragma unroll
            for (int q = 0; q < HH / 4; ++q) {
                float4 ha = h1v[q];
                float4 hb = h2v[q];
                y0 = fmaf(ha.x, wA[4*q+0], y0);
                y1 = fmaf(ha.y, wA[4*q+1], y1);
                y2 = fmaf(ha.z, wA[4*q+2], y2);
                y3 = fmaf(ha.w, wA[4*q+3], y3);
                y0 = fmaf(hb.x, wB[4*q+0], y0);
                y1 = fmaf(hb.y, wB[4*q+1], y1);
                y2 = fmaf(hb.z, wB[4*q+2], y2);
                y3 = fmaf(hb.w, wB[4*q+3], y3);
            }
            float z2v = bias + ((y0 + y1) + (y2 + y3));

            float bgt = (g == 2) ? fmaxf(z2v, 0.f) : sigmoidf_(z2v);
            float b1_ = qpx1(bgt), b2_ = qpx2(bgt), b3_ = qpx3(bgt);
            c2 = b1_ * c2 + bgt * b2_;
            float h2n = b3_ * fmaxf(c2, 0.f);
            if (g == 0) h2b[wb][elem][u] = h2n;
        }
        __syncthreads();
    }

    // final h2(255) written at iter 256 -> h2b[0]
    if (tid < EPB) {
        float acc = bd[0];
#pragma unroll
        for (int k = 0; k < HH; ++k) acc += h2b[0][tid][k] * Wd[k];
        out[b0 + tid] = acc;
    }
}

// ================= Fallback (ws too small): fused kernel =================
__global__ __launch_bounds__(PBLK, 2) void lstm2_fused_fb(
    const float* __restrict__ x,
    const float* __restrict__ W1, const float* __restrict__ U1, const float* __restrict__ b1,
    const float* __restrict__ W2, const float* __restrict__ U2, const float* __restrict__ b2,
    const float* __restrict__ Wd, const float* __restrict__ bd,
    float* __restrict__ out)
{
    const int tid  = threadIdx.x;
    const int elem = tid / G4;
    const int j    = tid - elem * G4;
    const int g    = j & 3;
    const int u    = j >> 2;
    const int col  = g * HH + u;
    const int b0   = blockIdx.x * EPB;

    __shared__ float xs[2][EPB][FF];
    __shared__ float h1b[2][EPB][24];
    __shared__ float h2b[2][EPB][24];

    float w1[FF], u1[HH], w2[HH], u2[HH];
#pragma unroll
    for (int f = 0; f < FF; ++f) w1[f] = W1[f * G4 + col];
#pragma unroll
    for (int k = 0; k < HH; ++k) u1[k] = U1[k * G4 + col];
#pragma unroll
    for (int k = 0; k < HH; ++k) w2[k] = W2[k * G4 + col];
#pragma unroll
    for (int k = 0; k < HH; ++k) u2[k] = U2[k * G4 + col];
    const float bias1 = b1[col];
    const float bias2 = b2[col];

    for (int i = tid; i < 2 * EPB * 24; i += PBLK) ((float*)h1b)[i] = 0.f;
    for (int i = tid; i < 2 * EPB * 24; i += PBLK) ((float*)h2b)[i] = 0.f;
    if (tid < EPB * FF) {
        int e2 = tid >> 6, f2 = tid & 63;
        xs[0][e2][f2] = x[((long)(b0 + e2) * TT + 0) * FF + f2];
    }
    __syncthreads();

    float c1 = 0.f, c2 = 0.f;
    for (int t = 0; t < TT; ++t) {
        const int cur = t & 1;
        float xpre = 0.f;
        if (t + 1 < TT && tid < EPB * FF) {
            int e2 = tid >> 6, f2 = tid & 63;
            xpre = x[((long)(b0 + e2) * TT + (t + 1)) * FF + f2];
        }
        float zz0 = 0.f, zz1 = 0.f, zz2 = 0.f, zz3 = 0.f;
        const float4* xv = (const float4*)xs[cur][elem];
#pragma unroll
        for (int q = 0; q < FF / 4; ++q) {
            float4 xx = xv[q];
            zz0 = fmaf(xx.x, w1[4*q+0], zz0);
            zz1 = fmaf(xx.y, w1[4*q+1], zz1);
            zz2 = fmaf(xx.z, w1[4*q+2], zz2);
            zz3 = fmaf(xx.w, w1[4*q+3], zz3);
        }
        const float4* hv = (const float4*)h1b[cur][elem];
#pragma unroll
        for (int q = 0; q < HH / 4; ++q) {
            float4 hh = hv[q];
            zz0 = fmaf(hh.x, u1[4*q+0], zz0);
            zz1 = fmaf(hh.y, u1[4*q+1], zz1);
            zz2 = fmaf(hh.z, u1[4*q+2], zz2);
            zz3 = fmaf(hh.w, u1[4*q+3], zz3);
        }
        float z = bias1 + ((zz0 + zz1) + (zz2 + zz3));
        float a = (g == 2) ? fmaxf(z, 0.f) : sigmoidf_(z);
        float a1 = qpx1(a), a2 = qpx2(a), a3 = qpx3(a);
        c1 = a1 * c1 + a * a2;
        float h1n = a3 * fmaxf(c1, 0.f);
        if (g == 0) h1b[cur ^ 1][elem][u] = h1n;
        __syncthreads();
        if (t + 1 < TT && tid < EPB * FF) xs[cur ^ 1][tid >> 6][tid & 63] = xpre;

        float y0 = 0.f, y1 = 0.f, y2 = 0.f, y3 = 0.f;
        const float4* h1v = (const float4*)h1b[cur ^ 1][elem];
        const float4* h2v = (const float4*)h2b[cur][elem];
#pragma unroll
        for (int q = 0; q < HH / 4; ++q) {
            float4 ha = h1v[q];
            float4 hb = h2v[q];
            y0 = fmaf(ha.x, w2[4*q+0], y0);
            y1 = fmaf(ha.y, w2[4*q+1], y1);
            y2 = fmaf(ha.z, w2[4*q+2], y2);
            y3 = fmaf(ha.w, w2[4*q+3], y3);
            y0 = fmaf(hb.x, u2[4*q+0], y0);
            y1 = fmaf(hb.y, u2[4*q+1], y1);
            y2 = fmaf(hb.z, u2[4*q+2], y2);
            y3 = fmaf(hb.w, u2[4*q+3], y3);
        }
        float z2v = bias2 + ((y0 + y1) + (y2 + y3));
        float bgt = (g == 2) ? fmaxf(z2v, 0.f) : sigmoidf_(z2v);
        float b1_ = qpx1(bgt), b2_ = qpx2(bgt), b3_ = qpx3(bgt);
        c2 = b1_ * c2 + bgt * b2_;
        float h2n = b3_ * fmaxf(c2, 0.f);
        if (g == 0) h2b[cur ^ 1][elem][u] = h2n;
        __syncthreads();
    }
    if (j == 0) {
        float acc = bd[0];
#pragma unroll
        for (int k = 0; k < HH; ++k) acc += h2b[0][elem][k] * Wd[k];
        out[b0 + elem] = acc;
    }
}

extern "C" void kernel_launch(void* const* d_in, const int* in_sizes, int n_in,
                              void* d_out, int out_size, void* d_ws, size_t ws_size,
                              hipStream_t stream) {
    const float* x  = (const float*)d_in[0];
    const float* W1 = (const float*)d_in[1];
    const float* U1 = (const float*)d_in[2];
    const float* b1 = (const float*)d_in[3];
    const float* W2 = (const float*)d_in[4];
    const float* U2 = (const float*)d_in[5];
    const float* b2 = (const float*)d_in[6];
    const float* Wd = (const float*)d_in[7];
    const float* bd = (const float*)d_in[8];
    float* out = (float*)d_out;
    const int B = in_sizes[0] / (TT * FF);   // 2048

    const size_t need = (size_t)B * TT * G4 * sizeof(float);  // 167.8 MB
    if (ws_size >= need) {
        float* xw = (float*)d_ws;
        hipLaunchKernelGGL(proj_x, dim3(B * (TT / TC)), dim3(PBLK), 0, stream,
                           x, W1, b1, xw, B);
        hipLaunchKernelGGL(lstm2_pc, dim3(B / EPB), dim3(RBLK), 0, stream,
                           xw, U1, W2, U2, b2, Wd, bd, out, B);
    } else {
        hipLaunchKernelGGL(lstm2_fused_fb, dim3(B / EPB), dim3(PBLK), 0, stream,
                           x, W1, U1, b1, W2, U2, b2, Wd, bd, out);
    }
}